// Round 3
// baseline (1341.619 us; speedup 1.0000x reference)
//
#include <hip/hip_runtime.h>
#include <hip/hip_bf16.h>
#include <cstddef>
#include <cstdint>

// Problem constants (fixed by setup_inputs)
#define NB 8
#define LQ 8192
#define DMODEL 256
#define NHD 8
#define NLV 4
#define NPT 4
#define DH 32
#define LEN_IN 19560          // 92*160 + 46*80 + 23*40 + 12*20
#define NQ (NB * LQ)          // 65536
#define MV (NB * LEN_IN)      // 156480

__device__ __forceinline__ unsigned short f2bf_bits(float f) {
  __hip_bfloat16 h = __float2bfloat16(f);
  return *(unsigned short*)&h;
}

// ---------------------------------------------------------------------------
// fp32 GEMM, C[M,N] = A[M,K=256] @ B[256,N] + bias[N]. fp32 output.
// ---------------------------------------------------------------------------
__global__ __launch_bounds__(256) void gemm_bias_k256(
    const float* __restrict__ A, const float* __restrict__ Bm,
    const float* __restrict__ bias, float* __restrict__ C, int N) {
  constexpr int K = 256;
  __shared__ float As[16][68];  // [k][m]
  __shared__ float Bs[16][68];  // [k][n]

  const int bm = blockIdx.y * 64;
  const int bn = blockIdx.x * 64;
  const int tid = threadIdx.x;
  const int tx = tid & 15;
  const int ty = tid >> 4;
  const int am = tid >> 2;
  const int ak = (tid & 3) << 2;
  const int bk = tid >> 4;
  const int bn4 = (tid & 15) << 2;

  float acc[4][4] = {};

  for (int k0 = 0; k0 < K; k0 += 16) {
    float4 av = *(const float4*)(A + (size_t)(bm + am) * K + (k0 + ak));
    float4 bv = *(const float4*)(Bm + (size_t)(k0 + bk) * N + (bn + bn4));
    __syncthreads();
    As[ak + 0][am] = av.x;
    As[ak + 1][am] = av.y;
    As[ak + 2][am] = av.z;
    As[ak + 3][am] = av.w;
    *(float4*)&Bs[bk][bn4] = bv;
    __syncthreads();
#pragma unroll
    for (int kk = 0; kk < 16; ++kk) {
      float4 a4 = *(const float4*)&As[kk][ty << 2];
      float4 b4 = *(const float4*)&Bs[kk][tx << 2];
      const float a[4] = {a4.x, a4.y, a4.z, a4.w};
      const float b[4] = {b4.x, b4.y, b4.z, b4.w};
#pragma unroll
      for (int i = 0; i < 4; ++i)
#pragma unroll
        for (int j = 0; j < 4; ++j) acc[i][j] += a[i] * b[j];
    }
  }

  float4 bv = *(const float4*)(bias + bn + (tx << 2));
  const float bb[4] = {bv.x, bv.y, bv.z, bv.w};
#pragma unroll
  for (int i = 0; i < 4; ++i) {
    float4 o;
    o.x = acc[i][0] + bb[0];
    o.y = acc[i][1] + bb[1];
    o.z = acc[i][2] + bb[2];
    o.w = acc[i][3] + bb[3];
    *(float4*)(C + (size_t)(bm + (ty << 2) + i) * N + bn + (tx << 2)) = o;
  }
}

// ---------------------------------------------------------------------------
// Same GEMM but bf16 output (fp32 compute, round on store). Used for value.
// ---------------------------------------------------------------------------
__global__ __launch_bounds__(256) void gemm_bias_k256_bf16out(
    const float* __restrict__ A, const float* __restrict__ Bm,
    const float* __restrict__ bias, __hip_bfloat16* __restrict__ C, int N) {
  constexpr int K = 256;
  __shared__ float As[16][68];
  __shared__ float Bs[16][68];

  const int bm = blockIdx.y * 64;
  const int bn = blockIdx.x * 64;
  const int tid = threadIdx.x;
  const int tx = tid & 15;
  const int ty = tid >> 4;
  const int am = tid >> 2;
  const int ak = (tid & 3) << 2;
  const int bk = tid >> 4;
  const int bn4 = (tid & 15) << 2;

  float acc[4][4] = {};

  for (int k0 = 0; k0 < K; k0 += 16) {
    float4 av = *(const float4*)(A + (size_t)(bm + am) * K + (k0 + ak));
    float4 bv = *(const float4*)(Bm + (size_t)(k0 + bk) * N + (bn + bn4));
    __syncthreads();
    As[ak + 0][am] = av.x;
    As[ak + 1][am] = av.y;
    As[ak + 2][am] = av.z;
    As[ak + 3][am] = av.w;
    *(float4*)&Bs[bk][bn4] = bv;
    __syncthreads();
#pragma unroll
    for (int kk = 0; kk < 16; ++kk) {
      float4 a4 = *(const float4*)&As[kk][ty << 2];
      float4 b4 = *(const float4*)&Bs[kk][tx << 2];
      const float a[4] = {a4.x, a4.y, a4.z, a4.w};
      const float b[4] = {b4.x, b4.y, b4.z, b4.w};
#pragma unroll
      for (int i = 0; i < 4; ++i)
#pragma unroll
        for (int j = 0; j < 4; ++j) acc[i][j] += a[i] * b[j];
    }
  }

  float4 bv = *(const float4*)(bias + bn + (tx << 2));
  const float bb[4] = {bv.x, bv.y, bv.z, bv.w};
#pragma unroll
  for (int i = 0; i < 4; ++i) {
    ushort4 o;
    o.x = f2bf_bits(acc[i][0] + bb[0]);
    o.y = f2bf_bits(acc[i][1] + bb[1]);
    o.z = f2bf_bits(acc[i][2] + bb[2]);
    o.w = f2bf_bits(acc[i][3] + bb[3]);
    *(ushort4*)(C + (size_t)(bm + (ty << 2) + i) * N + bn + (tx << 2)) = o;
  }
}

// ---------------------------------------------------------------------------
// Softmax over contiguous groups of 16 (in-place). One thread per group.
// ---------------------------------------------------------------------------
__global__ __launch_bounds__(256) void softmax16(float* __restrict__ a) {
  const int g = blockIdx.x * blockDim.x + threadIdx.x;
  float* p = a + (size_t)g * 16;
  float v[16];
  float m = -1e30f;
#pragma unroll
  for (int i = 0; i < 16; ++i) {
    v[i] = p[i];
    m = fmaxf(m, v[i]);
  }
  float s = 0.f;
#pragma unroll
  for (int i = 0; i < 16; ++i) {
    v[i] = expf(v[i] - m);
    s += v[i];
  }
  const float inv = 1.f / s;
#pragma unroll
  for (int i = 0; i < 16; ++i) p[i] = v[i] * inv;
}

// ---------------------------------------------------------------------------
// Bilinear sampling, descriptor-precompute variant, bf16 value.
// One block per query; phase 1: 128 threads compute one point-descriptor each
// (4 clipped element offsets + 4 combined weights) into LDS; phase 2: 256
// threads = 8 heads x 32 ch do 4 gathers + 4 FMAs per point.
// ---------------------------------------------------------------------------
__global__ __launch_bounds__(256) void msda_sample_bf16(
    const float* __restrict__ refp,          // (NB, LQ, NLV, 2)
    const float* __restrict__ attnw,         // (NQ, 128) softmaxed
    const float* __restrict__ off,           // (NQ, 256)
    const __hip_bfloat16* __restrict__ value,// (NB, LEN_IN, 256) bf16
    float* __restrict__ mid) {               // (NQ, 256)
  const int q = blockIdx.x;
  const int tid = threadIdx.x;

  __shared__ int s_idx[128][4];
  __shared__ float s_wgt[128][4];

  if (tid < 128) {
    const int t = tid;                 // t == (h*NLV + l)*NPT + p
    const int l = (t >> 2) & 3;
    constexpr int Hs[4] = {92, 46, 23, 12};
    constexpr int Ws[4] = {160, 80, 40, 20};
    constexpr int S0[4] = {0, 14720, 18400, 19320};
    const int Hl = Hs[l], Wl = Ws[l], s0 = S0[l];

    const float rx = refp[(size_t)q * 8 + l * 2 + 0];
    const float ry = refp[(size_t)q * 8 + l * 2 + 1];
    const float ox = off[(size_t)q * 256 + 2 * t + 0];
    const float oy = off[(size_t)q * 256 + 2 * t + 1];
    const float w = attnw[(size_t)q * 128 + t];

    // x = (ref_x + off_x/W)*W - 0.5 == ref_x*W + off_x - 0.5
    const float x = rx * (float)Wl + ox - 0.5f;
    const float y = ry * (float)Hl + oy - 0.5f;
    const float xf = floorf(x), yf = floorf(y);
    const float wx = x - xf, wy = y - yf;
    const int x0 = (int)xf, y0 = (int)yf;
    const int x1 = x0 + 1, y1 = y0 + 1;
    const bool vx0 = (x0 >= 0) & (x0 < Wl), vx1 = (x1 >= 0) & (x1 < Wl);
    const bool vy0 = (y0 >= 0) & (y0 < Hl), vy1 = (y1 >= 0) & (y1 < Hl);
    const int cx0 = min(max(x0, 0), Wl - 1), cx1 = min(max(x1, 0), Wl - 1);
    const int cy0 = min(max(y0, 0), Hl - 1), cy1 = min(max(y1, 0), Hl - 1);

    s_idx[t][0] = (s0 + cy0 * Wl + cx0) << 8;  // *DMODEL
    s_idx[t][1] = (s0 + cy0 * Wl + cx1) << 8;
    s_idx[t][2] = (s0 + cy1 * Wl + cx0) << 8;
    s_idx[t][3] = (s0 + cy1 * Wl + cx1) << 8;
    s_wgt[t][0] = (vx0 & vy0) ? w * (1.f - wx) * (1.f - wy) : 0.f;
    s_wgt[t][1] = (vx1 & vy0) ? w * wx * (1.f - wy) : 0.f;
    s_wgt[t][2] = (vx0 & vy1) ? w * (1.f - wx) * wy : 0.f;
    s_wgt[t][3] = (vx1 & vy1) ? w * wx * wy : 0.f;
  }
  __syncthreads();

  const int b = q >> 13;  // q / LQ
  // Channel for this lane is tid = h*32 + dh  (head offset INCLUDED — the
  // round-2 bug was using (tid&31) here, which sampled head 0's channels
  // for every head).
  const __hip_bfloat16* vbase = value + (size_t)b * LEN_IN * DMODEL + tid;
  const int h = tid >> 5;

  float acc = 0.f;
#pragma unroll
  for (int p = 0; p < 16; ++p) {
    const int d = (h << 4) + p;
    const int4 idx = *(const int4*)s_idx[d];
    const float4 wv = *(const float4*)s_wgt[d];
    const float v00 = __bfloat162float(vbase[idx.x]);
    const float v10 = __bfloat162float(vbase[idx.y]);
    const float v01 = __bfloat162float(vbase[idx.z]);
    const float v11 = __bfloat162float(vbase[idx.w]);
    acc += wv.x * v00 + wv.y * v10 + wv.z * v01 + wv.w * v11;
  }
  mid[(size_t)q * 256 + tid] = acc;
}

// ---------------------------------------------------------------------------
// Launch
// ---------------------------------------------------------------------------
extern "C" void kernel_launch(void* const* d_in, const int* in_sizes, int n_in,
                              void* d_out, int out_size, void* d_ws,
                              size_t ws_size, hipStream_t stream) {
  const float* query = (const float*)d_in[0];
  const float* refp = (const float*)d_in[1];
  const float* inflat = (const float*)d_in[2];
  const float* W_off = (const float*)d_in[5];
  const float* b_off = (const float*)d_in[6];
  const float* W_attn = (const float*)d_in[7];
  const float* b_attn = (const float*)d_in[8];
  const float* W_val = (const float*)d_in[9];
  const float* b_val = (const float*)d_in[10];
  const float* W_out = (const float*)d_in[11];
  const float* b_out = (const float*)d_in[12];
  float* out = (float*)d_out;

  // Workspace layout:
  //   value bf16 : MV*256*2  =  80,117,760 B
  //   attn fp32  : NQ*128*4  =  33,554,432 B
  //   off  fp32  : NQ*256*4  =  67,108,864 B
  //   mid  fp32  : NQ*256*4  =  67,108,864 B   total 247,889,920 B
  char* ws = (char*)d_ws;
  __hip_bfloat16* v_ws = (__hip_bfloat16*)(ws);
  float* attn_ws = (float*)(ws + 80117760ULL);
  float* off_ws = (float*)(ws + 113672192ULL);
  float* mid_ws = (float*)(ws + 180781056ULL);

  // 1. value = input_flatten @ W_val + b_val  -> bf16   (156480 x 256)
  gemm_bias_k256_bf16out<<<dim3(256 / 64, MV / 64), 256, 0, stream>>>(
      inflat, W_val, b_val, v_ws, 256);
  // 2. attn logits = query @ W_attn + b_attn           (65536 x 128)
  gemm_bias_k256<<<dim3(128 / 64, NQ / 64), 256, 0, stream>>>(
      query, W_attn, b_attn, attn_ws, 128);
  // 3. offsets = query @ W_off + b_off                 (65536 x 256)
  gemm_bias_k256<<<dim3(256 / 64, NQ / 64), 256, 0, stream>>>(
      query, W_off, b_off, off_ws, 256);
  // 4. softmax over groups of 16 (in place)
  softmax16<<<(NQ * NHD) / 256, 256, 0, stream>>>(attn_ws);
  // 5. bilinear sampling + weighted sum -> mid         (65536 x 256)
  msda_sample_bf16<<<NQ, 256, 0, stream>>>(refp, attn_ws, off_ws, v_ws,
                                           mid_ws);
  // 6. out = mid @ W_out + b_out                       (65536 x 256)
  gemm_bias_k256<<<dim3(256 / 64, NQ / 64), 256, 0, stream>>>(mid_ws, W_out,
                                                              b_out, out, 256);
}

// Round 4
// 707.554 us; speedup vs baseline: 1.8961x; 1.8961x over previous
//
#include <hip/hip_runtime.h>
#include <hip/hip_bf16.h>
#include <cstddef>
#include <cstdint>

#define NB 8
#define LQ 8192
#define DMODEL 256
#define NHD 8
#define NLV 4
#define NPT 4
#define LEN_IN 19560          // 92*160 + 46*80 + 23*40 + 12*20
#define NQ (NB * LQ)          // 65536
#define MV (NB * LEN_IN)      // 156480
#define MVP 156544            // MV padded to multiple of 128 (1223*128)

using bf16x8 = __attribute__((ext_vector_type(8))) short;
using f32x4  = __attribute__((ext_vector_type(4))) float;

typedef const __attribute__((address_space(1))) void* gas_ptr;
typedef __attribute__((address_space(3))) void* las_ptr;

__device__ __forceinline__ void gl_lds16(const void* g, void* l) {
  __builtin_amdgcn_global_load_lds((gas_ptr)g, (las_ptr)l, 16, 0, 0);
}
__device__ __forceinline__ float bflo(unsigned u) {
  union { unsigned i; float f; } c; c.i = u << 16; return c.f;
}
__device__ __forceinline__ float bfhi(unsigned u) {
  union { unsigned i; float f; } c; c.i = u & 0xffff0000u; return c.f;
}

// ---------------------------------------------------------------------------
// fp32 -> bf16 row-major convert with zero-padded tail rows.
// Thread converts 8 elements. Grid covers padded element count / 8.
// ---------------------------------------------------------------------------
__global__ __launch_bounds__(256) void convert_bf16_pad(
    const float* __restrict__ src, __hip_bfloat16* __restrict__ dst,
    long src_elems) {
  const long idx8 = (long)(blockIdx.x * 256 + threadIdx.x) * 8;
  ushort4 o0, o1;
  if (idx8 < src_elems) {
    float4 f0 = *(const float4*)(src + idx8);
    float4 f1 = *(const float4*)(src + idx8 + 4);
    o0 = {__bfloat16_as_ushort(__float2bfloat16(f0.x)),
          __bfloat16_as_ushort(__float2bfloat16(f0.y)),
          __bfloat16_as_ushort(__float2bfloat16(f0.z)),
          __bfloat16_as_ushort(__float2bfloat16(f0.w))};
    o1 = {__bfloat16_as_ushort(__float2bfloat16(f1.x)),
          __bfloat16_as_ushort(__float2bfloat16(f1.y)),
          __bfloat16_as_ushort(__float2bfloat16(f1.z)),
          __bfloat16_as_ushort(__float2bfloat16(f1.w))};
  } else {
    o0 = {0, 0, 0, 0};
    o1 = {0, 0, 0, 0};
  }
  *(ushort4*)((unsigned short*)dst + idx8) = o0;
  *(ushort4*)((unsigned short*)dst + idx8 + 4) = o1;
}

// ---------------------------------------------------------------------------
// W[256][N] fp32 -> Bt[N][256] bf16 (tiny; naive is fine)
// ---------------------------------------------------------------------------
__global__ __launch_bounds__(256) void transpose_bf16(
    const float* __restrict__ W, __hip_bfloat16* __restrict__ Bt, int N) {
  const int o = blockIdx.x * 256 + threadIdx.x;  // grid = N blocks
  const int n = o >> 8, k = o & 255;
  Bt[o] = __float2bfloat16(W[(size_t)k * N + n]);
}

// ---------------------------------------------------------------------------
// MFMA bf16 GEMM: C[M,N] = A[M,256] @ B[256,N] + bias.
// A: bf16 row-major [M][256]; Bt: bf16 col-major [N][256].
// Block 256 thr = 4 waves, tile 128x128, BK=32, global_load_lds width 16.
// OUT_MODE: 0 = fp32 row-major, 1 = bf16 row-major, 2 = bf16 value_h scatter.
// ---------------------------------------------------------------------------
template <int OUT_MODE>
__global__ __launch_bounds__(256) void gemm_mfma(
    const __hip_bfloat16* __restrict__ A, const __hip_bfloat16* __restrict__ Bt,
    const float* __restrict__ bias, void* __restrict__ Cout, int N,
    int M_valid) {
  __shared__ __hip_bfloat16 As[128 * 32];  // [m][k] 64 B/row (no pad: lds-dma)
  __shared__ __hip_bfloat16 Bs[128 * 32];  // [n][k]

  const int tid = threadIdx.x;
  const int wv = tid >> 6;
  const int lane = tid & 63;
  const int quad = lane >> 4;
  const int l16 = lane & 15;
  const int bm = blockIdx.y * 128;
  const int bn = blockIdx.x * 128;
  const int rw = (wv & 1) * 64;   // wave's row offset in tile
  const int cw = (wv >> 1) * 64;  // wave's col offset in tile

  // staging: slot s = tid (call 1), tid+256 (call 2); m = s>>2, k8 = (s&3)*8
  const __hip_bfloat16* gA = A + (size_t)(bm + (tid >> 2)) * 256 + (tid & 3) * 8;
  const __hip_bfloat16* gB = Bt + (size_t)(bn + (tid >> 2)) * 256 + (tid & 3) * 8;
  char* ldsA0 = (char*)As + wv * 1024;
  char* ldsB0 = (char*)Bs + wv * 1024;

  f32x4 acc[4][4] = {};

#pragma unroll 1
  for (int k0 = 0; k0 < 256; k0 += 32) {
    __syncthreads();  // all waves done reading LDS before overwrite
    gl_lds16(gA + k0, ldsA0);
    gl_lds16(gA + 64 * 256 + k0, ldsA0 + 4096);
    gl_lds16(gB + k0, ldsB0);
    gl_lds16(gB + 64 * 256 + k0, ldsB0 + 4096);
    __syncthreads();  // vmcnt(0) drain: tiles resident

    bf16x8 af[4], bfr[4];
#pragma unroll
    for (int t = 0; t < 4; ++t) {
      af[t] = *(const bf16x8*)(As + (rw + t * 16 + l16) * 32 + quad * 8);
      bfr[t] = *(const bf16x8*)(Bs + (cw + t * 16 + l16) * 32 + quad * 8);
    }
#pragma unroll
    for (int i = 0; i < 4; ++i)
#pragma unroll
      for (int j = 0; j < 4; ++j)
        acc[i][j] = __builtin_amdgcn_mfma_f32_16x16x32_bf16(af[i], bfr[j],
                                                            acc[i][j], 0, 0, 0);
  }

  // Epilogue. C/D layout: col = lane&15, row = quad*4 + reg.
#pragma unroll
  for (int j = 0; j < 4; ++j) {
    const int col = bn + cw + j * 16 + l16;
    const float bb = bias[col];
#pragma unroll
    for (int i = 0; i < 4; ++i) {
#pragma unroll
      for (int r = 0; r < 4; ++r) {
        const int row = bm + rw + i * 16 + quad * 4 + r;
        const float v = acc[i][j][r] + bb;
        if (OUT_MODE == 0) {
          ((float*)Cout)[(size_t)row * N + col] = v;
        } else if (OUT_MODE == 1) {
          ((__hip_bfloat16*)Cout)[(size_t)row * N + col] = __float2bfloat16(v);
        } else {
          if (row < M_valid) {
            const int b = row / LEN_IN;
            const int pix = row - b * LEN_IN;
            const int h = col >> 5, ch = col & 31;
            ((__hip_bfloat16*)Cout)[(((size_t)(b * 8 + h) * LEN_IN + pix) << 5) +
                                    ch] = __float2bfloat16(v);
          }
        }
      }
    }
  }
}

// ---------------------------------------------------------------------------
// Sampler: fused softmax + descriptor precompute + paired-pixel gather.
// Block = 1 query, 256 thr. Phase 1 (tid<128): one (h,l,p) point each —
// softmax over 16-groups via shfl, bilinear descriptor into LDS.
// Phase 2: thread = (head h, ch-pair c, px); 32 uint loads (2 bf16 each);
// x0/x1 pixels adjacent (head-major value) -> 128 B contiguous per tap-row.
// ---------------------------------------------------------------------------
__global__ __launch_bounds__(256) void msda_sample3(
    const float* __restrict__ refp,            // (NQ, 8)
    const float* __restrict__ logits,          // (NQ, 128) fp32 raw
    const __hip_bfloat16* __restrict__ offb,   // (NQ, 256) bf16
    const __hip_bfloat16* __restrict__ vh,     // (NB*8, LEN_IN, 32)
    __hip_bfloat16* __restrict__ mid) {        // (NQ, 256) bf16
  const int q = blockIdx.x;
  const int tid = threadIdx.x;

  __shared__ int s_i[128][4];    // {byteoff_y0row, byteoff_y1row, byte_dx, -}
  __shared__ float s_w[128][4];  // {w00, w10, w01, w11} = {(x0y0),(x1y0),(x0y1),(x1y1)}

  if (tid < 128) {
    const int t = tid;  // (h*NLV + l)*NPT + p  == h*16 + l*4 + p
    const int l = (t >> 2) & 3;
    constexpr int Hs[4] = {92, 46, 23, 12};
    constexpr int Ws_[4] = {160, 80, 40, 20};
    constexpr int St[4] = {0, 14720, 18400, 19320};
    const int Hl = Hs[l], Wl = Ws_[l];

    // fused softmax over 16-groups (xor masks 1,2,4,8 stay in-group)
    const float lg = logits[(size_t)q * 128 + t];
    float mx = lg;
#pragma unroll
    for (int d = 1; d < 16; d <<= 1) mx = fmaxf(mx, __shfl_xor(mx, d));
    const float e = expf(lg - mx);
    float sm = e;
#pragma unroll
    for (int d = 1; d < 16; d <<= 1) sm += __shfl_xor(sm, d);
    const float w = e / sm;

    const float rx = refp[(size_t)q * 8 + 2 * l];
    const float ry = refp[(size_t)q * 8 + 2 * l + 1];
    const unsigned uo = *(const unsigned*)(offb + (size_t)q * 256 + 2 * t);
    const float ox = bflo(uo), oy = bfhi(uo);

    const float x = rx * (float)Wl + ox - 0.5f;
    const float y = ry * (float)Hl + oy - 0.5f;
    const float xf = floorf(x), yf = floorf(y);
    const float wx = x - xf, wy = y - yf;
    const int x0 = (int)xf, y0 = (int)yf;
    const int x1 = x0 + 1, y1 = y0 + 1;
    const bool vx0 = (x0 >= 0) & (x0 < Wl), vx1 = (x1 >= 0) & (x1 < Wl);
    const bool vy0 = (y0 >= 0) & (y0 < Hl), vy1 = (y1 >= 0) & (y1 < Hl);
    const int cx0 = min(max(x0, 0), Wl - 1), cx1 = min(max(x1, 0), Wl - 1);
    const int cy0 = min(max(y0, 0), Hl - 1), cy1 = min(max(y1, 0), Hl - 1);

    s_i[t][0] = (St[l] + cy0 * Wl + cx0) * 64;  // 64 B per pixel (32ch bf16)
    s_i[t][1] = (St[l] + cy1 * Wl + cx0) * 64;
    s_i[t][2] = (cx1 - cx0) * 64;               // 0 or 64
    s_w[t][0] = (vx0 & vy0) ? w * (1.f - wx) * (1.f - wy) : 0.f;
    s_w[t][1] = (vx1 & vy0) ? w * wx * (1.f - wy) : 0.f;
    s_w[t][2] = (vx0 & vy1) ? w * (1.f - wx) * wy : 0.f;
    s_w[t][3] = (vx1 & vy1) ? w * wx * wy : 0.f;
  }
  __syncthreads();

  const int h = tid >> 5, r = tid & 31, c = r >> 1, px = r & 1;
  const int b = q >> 13;
  const char* vb =
      (const char*)vh + (size_t)(b * 8 + h) * LEN_IN * 64 + c * 4;

  float a0 = 0.f, a1 = 0.f;
#pragma unroll
  for (int pc = 0; pc < 4; ++pc) {
    unsigned u0[4], u1[4];
    float w0[4], w1[4];
#pragma unroll
    for (int j = 0; j < 4; ++j) {
      const int d = (h << 4) + pc * 4 + j;
      const int4 ii = *(const int4*)s_i[d];
      const float4 ww = *(const float4*)s_w[d];
      const int dxo = px ? ii.z : 0;
      u0[j] = *(const unsigned*)(vb + ii.x + dxo);
      u1[j] = *(const unsigned*)(vb + ii.y + dxo);
      w0[j] = px ? ww.y : ww.x;
      w1[j] = px ? ww.w : ww.z;
    }
#pragma unroll
    for (int j = 0; j < 4; ++j) {
      a0 += w0[j] * bflo(u0[j]) + w1[j] * bflo(u1[j]);
      a1 += w0[j] * bfhi(u0[j]) + w1[j] * bfhi(u1[j]);
    }
  }
  // combine x0/x1 partners (lane^1), pick this lane's channel (r = 2c+px)
  a0 += __shfl_xor(a0, 1);
  a1 += __shfl_xor(a1, 1);
  const float res = px ? a1 : a0;
  mid[(size_t)q * 256 + tid] = __float2bfloat16(res);
}

// ---------------------------------------------------------------------------
// Launch
// ---------------------------------------------------------------------------
extern "C" void kernel_launch(void* const* d_in, const int* in_sizes, int n_in,
                              void* d_out, int out_size, void* d_ws,
                              size_t ws_size, hipStream_t stream) {
  const float* query = (const float*)d_in[0];
  const float* refp = (const float*)d_in[1];
  const float* inflat = (const float*)d_in[2];
  const float* W_off = (const float*)d_in[5];
  const float* b_off = (const float*)d_in[6];
  const float* W_attn = (const float*)d_in[7];
  const float* b_attn = (const float*)d_in[8];
  const float* W_val = (const float*)d_in[9];
  const float* b_val = (const float*)d_in[10];
  const float* W_out = (const float*)d_in[11];
  const float* b_out = (const float*)d_in[12];
  float* out = (float*)d_out;

  // Workspace layout (bytes):
  char* ws = (char*)d_ws;
  __hip_bfloat16* Abuf = (__hip_bfloat16*)(ws);                  // [156544][256] bf16
  __hip_bfloat16* Qbuf = (__hip_bfloat16*)(ws + 80150528ULL);    // [65536][256]
  __hip_bfloat16* vh = (__hip_bfloat16*)(ws + 113704960ULL);     // [64][19560][32]
  float* logits = (float*)(ws + 193822720ULL);                   // [65536][128] f32
  __hip_bfloat16* offb = (__hip_bfloat16*)(ws + 227377152ULL);   // [65536][256]
  __hip_bfloat16* mid = (__hip_bfloat16*)(ws + 260931584ULL);    // [65536][256]
  __hip_bfloat16* Btv = (__hip_bfloat16*)(ws + 294486016ULL);    // [256][256]
  __hip_bfloat16* Bta = (__hip_bfloat16*)(ws + 294617088ULL);    // [128][256]
  __hip_bfloat16* Bto = (__hip_bfloat16*)(ws + 294682624ULL);    // [256][256]
  __hip_bfloat16* Btw = (__hip_bfloat16*)(ws + 294813696ULL);    // [256][256]
  // total 294,944,768 B

  // conversions (independent)
  convert_bf16_pad<<<(MVP * 256 / 8) / 256, 256, 0, stream>>>(
      inflat, Abuf, (long)MV * 256);
  convert_bf16_pad<<<(NQ * 256 / 8) / 256, 256, 0, stream>>>(
      query, Qbuf, (long)NQ * 256);
  transpose_bf16<<<256, 256, 0, stream>>>(W_val, Btv, 256);
  transpose_bf16<<<128, 256, 0, stream>>>(W_attn, Bta, 128);
  transpose_bf16<<<256, 256, 0, stream>>>(W_off, Bto, 256);
  transpose_bf16<<<256, 256, 0, stream>>>(W_out, Btw, 256);

  // 1. value = inflat @ W_val + b_val -> head-major bf16 value_h
  gemm_mfma<2><<<dim3(2, MVP / 128), 256, 0, stream>>>(Abuf, Btv, b_val, vh,
                                                       256, MV);
  // 2. attn logits = query @ W_attn + b_attn -> fp32 (softmax fused in sampler)
  gemm_mfma<0><<<dim3(1, NQ / 128), 256, 0, stream>>>(Qbuf, Bta, b_attn,
                                                      logits, 128, NQ);
  // 3. offsets = query @ W_off + b_off -> bf16
  gemm_mfma<1><<<dim3(2, NQ / 128), 256, 0, stream>>>(Qbuf, Bto, b_off, offb,
                                                      256, NQ);
  // 4. sampling (softmax fused) -> mid bf16
  msda_sample3<<<NQ, 256, 0, stream>>>(refp, logits, offb, vh, mid);
  // 5. out = mid @ W_out + b_out -> fp32 d_out
  gemm_mfma<0><<<dim3(2, NQ / 128), 256, 0, stream>>>(mid, Btw, b_out, out,
                                                      256, NQ);
}